// Round 4
// baseline (328.780 us; speedup 1.0000x reference)
//
#include <hip/hip_runtime.h>
#include <cstdint>

#define NN 32768
#define EE 524288
#define E2T (EE + NN)   // 557056 edges incl self loops
#define HID 128
#define LDSW 136        // u16 stride per LDS activation row (16B-aligned, bank-spread)
#define SLICE_U16 2097152  // 32768 nodes * 64 u16 per slice

typedef __attribute__((ext_vector_type(8)))  short s16x8;
typedef __attribute__((ext_vector_type(16))) float f32x16;

union V16 { uint4 u; s16x8 s; };

__device__ __forceinline__ float lrelu(float v) { return v > 0.0f ? v : 0.2f * v; }

// round-to-nearest-even f32 -> bf16
__device__ __forceinline__ unsigned short f2bf(float f) {
  unsigned int u = __float_as_uint(f);
  return (unsigned short)((u + 0x7fffu + ((u >> 16) & 1u)) >> 16);
}
__device__ __forceinline__ float bf2f(unsigned short h) {
  return __uint_as_float(((unsigned int)h) << 16);
}
#define BF_LO(u) __uint_as_float((u) << 16)
#define BF_HI(u) __uint_as_float((u) & 0xffff0000u)

// ---------------------------------------------------------------------------
// Pre-pack weights into MFMA B-fragment order, split bf16 hi/lo planes.
// Slot s: 0-3 = W1 colfrags, 4-7 = W2 colfrags, 8-23 = w_lin (s-8 = 4*head+cf).
// ---------------------------------------------------------------------------
__global__ void k_pack(const float* __restrict__ w1, const float* __restrict__ w2,
                       const float* __restrict__ wl,
                       unsigned short* __restrict__ phi, unsigned short* __restrict__ plo)
{
  int idx = blockIdx.x * 256 + threadIdx.x;   // grid covers exactly 98304
  int r  = idx & 7;
  int l  = (idx >> 3) & 63;
  int kb = (idx >> 9) & 7;
  int s  = idx >> 12;
  const float* m; int ld, n;
  if (s < 4)      { m = w1; ld = 128; n = 32 * s       + (l & 31); }
  else if (s < 8) { m = w2; ld = 128; n = 32 * (s - 4) + (l & 31); }
  else            { m = wl; ld = 512; n = 32 * (s - 8) + (l & 31); }
  int k = 16 * kb + 8 * (l >> 5) + r;
  float f = m[(size_t)k * ld + n];
  unsigned short hi = f2bf(f);
  unsigned short lo = f2bf(f - bf2f(hi));
  phi[idx] = hi;
  plo[idx] = lo;
}

// ---------------------------------------------------------------------------
// One 32x128 @ 128x(32 per wave) GEMM pass, split-bf16 3-term MFMA.
// ---------------------------------------------------------------------------
__device__ __forceinline__ void mm_pass(int slot, int lane,
    const unsigned short* __restrict__ phi, const unsigned short* __restrict__ plo,
    const unsigned short* hi_ls, const unsigned short* lo_ls, float accv[16])
{
  f32x16 acc1 = {0,0,0,0,0,0,0,0,0,0,0,0,0,0,0,0};
  f32x16 acc2 = {0,0,0,0,0,0,0,0,0,0,0,0,0,0,0,0};
  const int arow = lane & 31;
  const int h5 = lane >> 5;
  #pragma unroll
  for (int kb = 0; kb < 8; ++kb) {
    V16 bh, bl, ah, al;
    size_t boff = ((size_t)(slot * 8 + kb) * 64 + lane) * 8;
    bh.u = *(const uint4*)&phi[boff];
    bl.u = *(const uint4*)&plo[boff];
    int aoff = arow * LDSW + 16 * kb + 8 * h5;
    ah.u = *(const uint4*)&hi_ls[aoff];
    al.u = *(const uint4*)&lo_ls[aoff];
    acc1 = __builtin_amdgcn_mfma_f32_32x32x16_bf16(ah.s, bh.s, acc1, 0, 0, 0);
    acc2 = __builtin_amdgcn_mfma_f32_32x32x16_bf16(al.s, bh.s, acc2, 0, 0, 0);
    acc2 = __builtin_amdgcn_mfma_f32_32x32x16_bf16(ah.s, bl.s, acc2, 0, 0, 0);
  }
  #pragma unroll
  for (int r = 0; r < 16; ++r) accv[r] = acc1[r] + acc2[r];
}

// ---------------------------------------------------------------------------
// Fused MLP + w_lin: 32 rows/block, 4 waves = 4 col-fragments.
// Writes xh in SLICE-MAJOR layout: u16 addr = q*SLICE_U16 + row*64 + head*16 + cin
// where q = (in-head col)>>4, cin = (in-head col)&15.
// ---------------------------------------------------------------------------
__global__ __launch_bounds__(256) void k_fused(
    const float* __restrict__ x, const float* __restrict__ b1,
    const float* __restrict__ b2, const float* __restrict__ ln_g,
    const float* __restrict__ ln_b, const unsigned short* __restrict__ phi,
    const unsigned short* __restrict__ plo, unsigned short* __restrict__ xh)
{
  __shared__ unsigned short hi_ls[32 * LDSW];
  __shared__ unsigned short lo_ls[32 * LDSW];
  const int t = threadIdx.x;
  const int lane = t & 63;
  const int cf = t >> 6;
  const int row0 = blockIdx.x * 32;
  const int h5 = lane >> 5;
  float acc[16];

  // stage x strip -> hi/lo planes
  {
    const int r = t >> 3, seg = t & 7;
    const float* src = &x[(size_t)(row0 + r) * HID + seg * 16];
    #pragma unroll
    for (int i = 0; i < 4; ++i) {
      float4 v = *(const float4*)(src + 4 * i);
      int c = seg * 16 + 4 * i;
      ushort4 h, l;
      h.x = f2bf(v.x); l.x = f2bf(v.x - bf2f(h.x));
      h.y = f2bf(v.y); l.y = f2bf(v.y - bf2f(h.y));
      h.z = f2bf(v.z); l.z = f2bf(v.z - bf2f(h.z));
      h.w = f2bf(v.w); l.w = f2bf(v.w - bf2f(h.w));
      *(ushort4*)&hi_ls[r * LDSW + c] = h;
      *(ushort4*)&lo_ls[r * LDSW + c] = l;
    }
  }
  __syncthreads();

  // ---- layer 1 ----
  mm_pass(cf, lane, phi, plo, hi_ls, lo_ls, acc);
  __syncthreads();
  {
    const int col = 32 * cf + (lane & 31);
    const float bv = b1[col];
    #pragma unroll
    for (int r = 0; r < 16; ++r) {
      int row = (r & 3) + 8 * (r >> 2) + 4 * h5;
      float v = fmaxf(acc[r] + bv, 0.0f);
      unsigned short h = f2bf(v);
      hi_ls[row * LDSW + col] = h;
      lo_ls[row * LDSW + col] = f2bf(v - bf2f(h));
    }
  }
  __syncthreads();

  // ---- layer 2 ----
  mm_pass(4 + cf, lane, phi, plo, hi_ls, lo_ls, acc);
  __syncthreads();
  {
    const int col = 32 * cf + (lane & 31);
    const float bv = b2[col];
    #pragma unroll
    for (int r = 0; r < 16; ++r) {
      int row = (r & 3) + 8 * (r >> 2) + 4 * h5;
      float v = fmaxf(acc[r] + bv, 0.0f);
      unsigned short h = f2bf(v);
      hi_ls[row * LDSW + col] = h;
      lo_ls[row * LDSW + col] = f2bf(v - bf2f(h));
    }
  }
  __syncthreads();

  // ---- LayerNorm ----
  {
    float g0 = ln_g[2 * lane], g1 = ln_g[2 * lane + 1];
    float be0 = ln_b[2 * lane], be1 = ln_b[2 * lane + 1];
    for (int i = 0; i < 8; ++i) {
      int row = 8 * cf + i;
      unsigned int hp = *(const unsigned int*)&hi_ls[row * LDSW + 2 * lane];
      unsigned int lp = *(const unsigned int*)&lo_ls[row * LDSW + 2 * lane];
      float v0 = bf2f((unsigned short)(hp & 0xffffu)) + bf2f((unsigned short)(lp & 0xffffu));
      float v1 = bf2f((unsigned short)(hp >> 16))     + bf2f((unsigned short)(lp >> 16));
      float s = v0 + v1, q = v0 * v0 + v1 * v1;
      #pragma unroll
      for (int off = 1; off < 64; off <<= 1) {
        s += __shfl_xor(s, off);
        q += __shfl_xor(q, off);
      }
      float mu = s * (1.0f / 128.0f);
      float var = q * (1.0f / 128.0f) - mu * mu;
      float rs = rsqrtf(var + 1e-5f);
      float o0 = (v0 - mu) * rs * g0 + be0;
      float o1 = (v1 - mu) * rs * g1 + be1;
      unsigned short h0 = f2bf(o0), h1 = f2bf(o1);
      unsigned short q0 = f2bf(o0 - bf2f(h0)), q1 = f2bf(o1 - bf2f(h1));
      *(unsigned int*)&hi_ls[row * LDSW + 2 * lane] = (unsigned int)h0 | ((unsigned int)h1 << 16);
      *(unsigned int*)&lo_ls[row * LDSW + 2 * lane] = (unsigned int)q0 | ((unsigned int)q1 << 16);
    }
  }
  __syncthreads();

  // ---- w_lin: 4 head sub-passes, write slice-major bf16 xh ----
  for (int hd = 0; hd < 4; ++hd) {
    mm_pass(8 + 4 * hd + cf, lane, phi, plo, hi_ls, lo_ls, acc);
    const int col = 32 * cf + (lane & 31);   // in-head column 0..127
    const int q = col >> 4, cin = col & 15;
    unsigned short* base = xh + (size_t)q * SLICE_U16 + hd * 16 + cin;
    #pragma unroll
    for (int r = 0; r < 16; ++r) {
      int row = (r & 3) + 8 * (r >> 2) + 4 * h5;
      base[(size_t)(row0 + row) * 64] = f2bf(acc[r]);
    }
  }
}

// ---------------------------------------------------------------------------
// attention coefficients from slice-major bf16 xh: one wave per node
// ---------------------------------------------------------------------------
__global__ __launch_bounds__(256) void k_att(
    const unsigned short* __restrict__ xh, const float* __restrict__ att_s,
    const float* __restrict__ att_d, float* __restrict__ a_src,
    float* __restrict__ a_dst)
{
  const int lane = threadIdx.x & 63;
  const int n = blockIdx.x * 4 + (threadIdx.x >> 6);
  const int head = lane >> 4;
  const int c0 = 8 * (lane & 15);         // in-head channel base
  const int q = c0 >> 4, cin = c0 & 15;   // cin in {0,8}
  uint4 xv = *(const uint4*)&xh[(size_t)q * SLICE_U16 + (size_t)n * 64 + head * 16 + cin];
  float4 s1 = *(const float4*)&att_s[head * 128 + c0];
  float4 s2 = *(const float4*)&att_s[head * 128 + c0 + 4];
  float4 d1 = *(const float4*)&att_d[head * 128 + c0];
  float4 d2 = *(const float4*)&att_d[head * 128 + c0 + 4];
  float x0 = BF_LO(xv.x), x1 = BF_HI(xv.x), x2 = BF_LO(xv.y), x3 = BF_HI(xv.y);
  float x4 = BF_LO(xv.z), x5 = BF_HI(xv.z), x6 = BF_LO(xv.w), x7 = BF_HI(xv.w);
  float ps = x0*s1.x + x1*s1.y + x2*s1.z + x3*s1.w + x4*s2.x + x5*s2.y + x6*s2.z + x7*s2.w;
  float pd = x0*d1.x + x1*d1.y + x2*d1.z + x3*d1.w + x4*d2.x + x5*d2.y + x6*d2.z + x7*d2.w;
  #pragma unroll
  for (int off = 1; off < 16; off <<= 1) {
    ps += __shfl_xor(ps, off);
    pd += __shfl_xor(pd, off);
  }
  if ((lane & 15) == 0) {
    a_src[n * 4 + head] = ps;
    a_dst[n * 4 + head] = pd;
  }
}

// ---------------------------------------------------------------------------
// CSR build: histogram -> scan -> scatter (sorted by dst)
// ---------------------------------------------------------------------------
__global__ void k_hist(const int* __restrict__ ei, int* __restrict__ count)
{
  int i = blockIdx.x * 256 + threadIdx.x;
  if (i >= E2T) return;
  int dst = (i < EE) ? ei[EE + i] : (i - EE);
  atomicAdd(&count[dst], 1);
}

__global__ __launch_bounds__(256) void k_scan(const int* __restrict__ count,
                                              int* __restrict__ offsets,
                                              int* __restrict__ cursor)
{
  __shared__ int wtot[4];
  const int t = threadIdx.x;
  const int base = t * (NN / 256);
  int s = 0;
  for (int k = 0; k < NN / 256; ++k) s += count[base + k];
  const int lane = t & 63, w = t >> 6;
  int v = s;
  #pragma unroll
  for (int off = 1; off < 64; off <<= 1) {
    int u = __shfl_up(v, off);
    if (lane >= off) v += u;
  }
  if (lane == 63) wtot[w] = v;
  __syncthreads();
  int wpre = 0;
  for (int i = 0; i < w; ++i) wpre += wtot[i];
  int run = v + wpre - s;
  for (int k = 0; k < NN / 256; ++k) {
    offsets[base + k] = run;
    cursor[base + k] = run;
    run += count[base + k];
  }
  if (t == 255) offsets[NN] = run;
}

__global__ void k_scatter(const int* __restrict__ ei, int* __restrict__ cursor,
                          int* __restrict__ srcs)
{
  int i = blockIdx.x * 256 + threadIdx.x;
  if (i >= E2T) return;
  int s, d;
  if (i < EE) { s = ei[i]; d = ei[EE + i]; }
  else        { s = i - EE; d = s; }
  int pos = atomicAdd(&cursor[d], 1);
  srcs[pos] = s;
}

// ---------------------------------------------------------------------------
// GAT aggregation, XCD-sliced: slice q = blockIdx & 7 (one 4MB xh slice per
// XCD's L2). Slice q covers out-channels [16q,16q+16) for ALL 4 heads (128 B
// per node, contiguous). Wave = one dst node; lanes = 8 edge-subs x 8
// (head,chhalf) groups; uint4 = 8 bf16 channels per lane per edge.
// Head-mean merged in-wave via shfl (no atomics).
// ---------------------------------------------------------------------------
__global__ __launch_bounds__(256) void k_gat2(
    const unsigned short* __restrict__ xh, const float* __restrict__ a_src,
    const float* __restrict__ a_dst, const int* __restrict__ offsets,
    const int* __restrict__ srcs, const float* __restrict__ bias,
    float* __restrict__ out)
{
  __shared__ float ex_ls[4][64][4];
  __shared__ int src_ls[4][64];
  const int lane = threadIdx.x & 63;
  const int w = threadIdx.x >> 6;
  const int q = blockIdx.x & 7;
  const int n = (blockIdx.x >> 3) * 4 + w;
  const float4 adn = *(const float4*)&a_dst[n * 4];
  const int beg = offsets[n];
  const int deg = offsets[n + 1] - beg;
  const int hsel = (lane & 7) >> 1;   // head handled by this lane in phase B
  const unsigned short* slice = xh + (size_t)q * SLICE_U16 + (lane & 7) * 8;

  float acc[8] = {0, 0, 0, 0, 0, 0, 0, 0};
  float d0 = 0, d1 = 0, d2 = 0, d3 = 0;

  for (int j0 = 0; j0 < deg; j0 += 64) {
    int j = j0 + lane;
    float x0 = 0, x1 = 0, x2 = 0, x3 = 0;
    int s = 0;
    if (j < deg) {
      s = __builtin_nontemporal_load(&srcs[beg + j]);
      float4 as = *(const float4*)&a_src[s * 4];
      x0 = __expf(lrelu(as.x + adn.x));
      x1 = __expf(lrelu(as.y + adn.y));
      x2 = __expf(lrelu(as.z + adn.z));
      x3 = __expf(lrelu(as.w + adn.w));
      d0 += x0; d1 += x1; d2 += x2; d3 += x3;
    }
    ex_ls[w][lane][0] = x0; ex_ls[w][lane][1] = x1;
    ex_ls[w][lane][2] = x2; ex_ls[w][lane][3] = x3;
    src_ls[w][lane] = s;
    __builtin_amdgcn_wave_barrier();
    const int cnt8 = (min(64, deg - j0) + 7) >> 3;
    #pragma unroll 4
    for (int g = 0; g < cnt8; ++g) {
      int e = g * 8 + (lane >> 3);
      float a = ex_ls[w][e][hsel];
      int sv = src_ls[w][e];
      uint4 xv = *(const uint4*)(slice + (size_t)sv * 64);
      acc[0] = fmaf(a, BF_LO(xv.x), acc[0]);
      acc[1] = fmaf(a, BF_HI(xv.x), acc[1]);
      acc[2] = fmaf(a, BF_LO(xv.y), acc[2]);
      acc[3] = fmaf(a, BF_HI(xv.y), acc[3]);
      acc[4] = fmaf(a, BF_LO(xv.z), acc[4]);
      acc[5] = fmaf(a, BF_HI(xv.z), acc[5]);
      acc[6] = fmaf(a, BF_LO(xv.w), acc[6]);
      acc[7] = fmaf(a, BF_HI(xv.w), acc[7]);
    }
    __builtin_amdgcn_wave_barrier();
  }

  #pragma unroll
  for (int off = 1; off < 64; off <<= 1) {
    d0 += __shfl_xor(d0, off); d1 += __shfl_xor(d1, off);
    d2 += __shfl_xor(d2, off); d3 += __shfl_xor(d3, off);
  }
  float dsel = (hsel & 2) ? ((hsel & 1) ? d3 : d2) : ((hsel & 1) ? d1 : d0);
  float inv = 1.0f / (dsel + 1e-16f);
  #pragma unroll
  for (int m = 0; m < 8; ++m) {
    float v = acc[m] * inv;
    v += __shfl_xor(v, 2);    // merge heads (lane bits 1-2)
    v += __shfl_xor(v, 4);
    v += __shfl_xor(v, 8);    // merge edge-sub groups (lane bits 3-5)
    v += __shfl_xor(v, 16);
    v += __shfl_xor(v, 32);
    acc[m] = v;
  }
  if (lane < 2) {
    const int c0 = 16 * q + 8 * lane;
    float4 o1, o2;
    o1.x = 0.25f * acc[0] + bias[c0 + 0];
    o1.y = 0.25f * acc[1] + bias[c0 + 1];
    o1.z = 0.25f * acc[2] + bias[c0 + 2];
    o1.w = 0.25f * acc[3] + bias[c0 + 3];
    o2.x = 0.25f * acc[4] + bias[c0 + 4];
    o2.y = 0.25f * acc[5] + bias[c0 + 5];
    o2.z = 0.25f * acc[6] + bias[c0 + 6];
    o2.w = 0.25f * acc[7] + bias[c0 + 7];
    *(float4*)&out[(size_t)n * HID + c0]     = o1;
    *(float4*)&out[(size_t)n * HID + c0 + 4] = o2;
  }
}

// ---------------------------------------------------------------------------
extern "C" void kernel_launch(void* const* d_in, const int* in_sizes, int n_in,
                              void* d_out, int out_size, void* d_ws, size_t ws_size,
                              hipStream_t stream)
{
  const float* x     = (const float*)d_in[0];
  const int*   ei    = (const int*)  d_in[1];
  const float* w1    = (const float*)d_in[2];
  const float* b1    = (const float*)d_in[3];
  const float* w2    = (const float*)d_in[4];
  const float* b2    = (const float*)d_in[5];
  const float* ln_g  = (const float*)d_in[6];
  const float* ln_b  = (const float*)d_in[7];
  const float* w_lin = (const float*)d_in[8];
  const float* att_s = (const float*)d_in[9];
  const float* att_d = (const float*)d_in[10];
  const float* bias  = (const float*)d_in[11];
  float* out = (float*)d_out;

  char* ws = (char*)d_ws;
  size_t off = 0;
  auto alloc = [&](size_t bytes) -> char* {
    char* p = ws + off;
    off += (bytes + 255) & ~(size_t)255;
    return p;
  };
  unsigned short* xh  = (unsigned short*)alloc((size_t)8 * SLICE_U16 * 2);  // 32 MB
  unsigned short* phi = (unsigned short*)alloc(98304 * 2);
  unsigned short* plo = (unsigned short*)alloc(98304 * 2);
  float* a_src  = (float*)alloc((size_t)NN * 4 * 4);
  float* a_dst  = (float*)alloc((size_t)NN * 4 * 4);
  int* count    = (int*)alloc((size_t)NN * 4);
  int* offsets  = (int*)alloc((size_t)(NN + 1) * 4);
  int* cursor   = (int*)alloc((size_t)NN * 4);
  int* srcs     = (int*)alloc((size_t)E2T * 4);
  if (off > ws_size) return;

  hipMemsetAsync(count, 0, (size_t)NN * 4, stream);

  k_pack<<<384, 256, 0, stream>>>(w1, w2, w_lin, phi, plo);
  k_hist<<<(E2T + 255) / 256, 256, 0, stream>>>(ei, count);
  k_scan<<<1, 256, 0, stream>>>(count, offsets, cursor);
  k_fused<<<NN / 32, 256, 0, stream>>>(x, b1, b2, ln_g, ln_b, phi, plo, xh);
  k_scatter<<<(E2T + 255) / 256, 256, 0, stream>>>(ei, cursor, srcs);
  k_att<<<NN / 4, 256, 0, stream>>>(xh, att_s, att_d, a_src, a_dst);
  k_gat2<<<(NN / 4) * 8, 256, 0, stream>>>(xh, a_src, a_dst, offsets, srcs, bias, out);
}

// Round 5
// 273.575 us; speedup vs baseline: 1.2018x; 1.2018x over previous
//
#include <hip/hip_runtime.h>
#include <cstdint>

#define NN 32768
#define EE 524288
#define E2T (EE + NN)   // 557056 edges incl self loops
#define HID 128
#define LDSW 136        // u16 stride per LDS activation row (16B-aligned, bank-spread)
#define SLICE_U16 2097152  // 32768 nodes * 64 u16 per slice

typedef __attribute__((ext_vector_type(8)))  short s16x8;
typedef __attribute__((ext_vector_type(16))) float f32x16;

union V16 { uint4 u; s16x8 s; };

__device__ __forceinline__ float lrelu(float v) { return v > 0.0f ? v : 0.2f * v; }

// round-to-nearest-even f32 -> bf16
__device__ __forceinline__ unsigned short f2bf(float f) {
  unsigned int u = __float_as_uint(f);
  return (unsigned short)((u + 0x7fffu + ((u >> 16) & 1u)) >> 16);
}
__device__ __forceinline__ float bf2f(unsigned short h) {
  return __uint_as_float(((unsigned int)h) << 16);
}
#define BF_LO(u) __uint_as_float((u) << 16)
#define BF_HI(u) __uint_as_float((u) & 0xffff0000u)

// ---------------------------------------------------------------------------
// Pre-pack weights into MFMA B-fragment order, split bf16 hi/lo planes.
// ---------------------------------------------------------------------------
__global__ void k_pack(const float* __restrict__ w1, const float* __restrict__ w2,
                       const float* __restrict__ wl,
                       unsigned short* __restrict__ phi, unsigned short* __restrict__ plo)
{
  int idx = blockIdx.x * 256 + threadIdx.x;   // grid covers exactly 98304
  int r  = idx & 7;
  int l  = (idx >> 3) & 63;
  int kb = (idx >> 9) & 7;
  int s  = idx >> 12;
  const float* m; int ld, n;
  if (s < 4)      { m = w1; ld = 128; n = 32 * s       + (l & 31); }
  else if (s < 8) { m = w2; ld = 128; n = 32 * (s - 4) + (l & 31); }
  else            { m = wl; ld = 512; n = 32 * (s - 8) + (l & 31); }
  int k = 16 * kb + 8 * (l >> 5) + r;
  float f = m[(size_t)k * ld + n];
  unsigned short hi = f2bf(f);
  unsigned short lo = f2bf(f - bf2f(hi));
  phi[idx] = hi;
  plo[idx] = lo;
}

// ---------------------------------------------------------------------------
// One 32x128 @ 128x(32 per wave) GEMM pass, split-bf16 3-term MFMA.
// ---------------------------------------------------------------------------
__device__ __forceinline__ void mm_pass(int slot, int lane,
    const unsigned short* __restrict__ phi, const unsigned short* __restrict__ plo,
    const unsigned short* hi_ls, const unsigned short* lo_ls, float accv[16])
{
  f32x16 acc1 = {0,0,0,0,0,0,0,0,0,0,0,0,0,0,0,0};
  f32x16 acc2 = {0,0,0,0,0,0,0,0,0,0,0,0,0,0,0,0};
  const int arow = lane & 31;
  const int h5 = lane >> 5;
  #pragma unroll
  for (int kb = 0; kb < 8; ++kb) {
    V16 bh, bl, ah, al;
    size_t boff = ((size_t)(slot * 8 + kb) * 64 + lane) * 8;
    bh.u = *(const uint4*)&phi[boff];
    bl.u = *(const uint4*)&plo[boff];
    int aoff = arow * LDSW + 16 * kb + 8 * h5;
    ah.u = *(const uint4*)&hi_ls[aoff];
    al.u = *(const uint4*)&lo_ls[aoff];
    acc1 = __builtin_amdgcn_mfma_f32_32x32x16_bf16(ah.s, bh.s, acc1, 0, 0, 0);
    acc2 = __builtin_amdgcn_mfma_f32_32x32x16_bf16(al.s, bh.s, acc2, 0, 0, 0);
    acc2 = __builtin_amdgcn_mfma_f32_32x32x16_bf16(ah.s, bl.s, acc2, 0, 0, 0);
  }
  #pragma unroll
  for (int r = 0; r < 16; ++r) accv[r] = acc1[r] + acc2[r];
}

// ---------------------------------------------------------------------------
// Fused MLP + w_lin: 32 rows/block, 4 waves = 4 col-fragments.
// Writes xh in SLICE-MAJOR layout: u16 addr = q*SLICE_U16 + row*64 + head*16 + cin
// ---------------------------------------------------------------------------
__global__ __launch_bounds__(256) void k_fused(
    const float* __restrict__ x, const float* __restrict__ b1,
    const float* __restrict__ b2, const float* __restrict__ ln_g,
    const float* __restrict__ ln_b, const unsigned short* __restrict__ phi,
    const unsigned short* __restrict__ plo, unsigned short* __restrict__ xh)
{
  __shared__ unsigned short hi_ls[32 * LDSW];
  __shared__ unsigned short lo_ls[32 * LDSW];
  const int t = threadIdx.x;
  const int lane = t & 63;
  const int cf = t >> 6;
  const int row0 = blockIdx.x * 32;
  const int h5 = lane >> 5;
  float acc[16];

  // stage x strip -> hi/lo planes
  {
    const int r = t >> 3, seg = t & 7;
    const float* src = &x[(size_t)(row0 + r) * HID + seg * 16];
    #pragma unroll
    for (int i = 0; i < 4; ++i) {
      float4 v = *(const float4*)(src + 4 * i);
      int c = seg * 16 + 4 * i;
      ushort4 h, l;
      h.x = f2bf(v.x); l.x = f2bf(v.x - bf2f(h.x));
      h.y = f2bf(v.y); l.y = f2bf(v.y - bf2f(h.y));
      h.z = f2bf(v.z); l.z = f2bf(v.z - bf2f(h.z));
      h.w = f2bf(v.w); l.w = f2bf(v.w - bf2f(h.w));
      *(ushort4*)&hi_ls[r * LDSW + c] = h;
      *(ushort4*)&lo_ls[r * LDSW + c] = l;
    }
  }
  __syncthreads();

  // ---- layer 1 ----
  mm_pass(cf, lane, phi, plo, hi_ls, lo_ls, acc);
  __syncthreads();
  {
    const int col = 32 * cf + (lane & 31);
    const float bv = b1[col];
    #pragma unroll
    for (int r = 0; r < 16; ++r) {
      int row = (r & 3) + 8 * (r >> 2) + 4 * h5;
      float v = fmaxf(acc[r] + bv, 0.0f);
      unsigned short h = f2bf(v);
      hi_ls[row * LDSW + col] = h;
      lo_ls[row * LDSW + col] = f2bf(v - bf2f(h));
    }
  }
  __syncthreads();

  // ---- layer 2 ----
  mm_pass(4 + cf, lane, phi, plo, hi_ls, lo_ls, acc);
  __syncthreads();
  {
    const int col = 32 * cf + (lane & 31);
    const float bv = b2[col];
    #pragma unroll
    for (int r = 0; r < 16; ++r) {
      int row = (r & 3) + 8 * (r >> 2) + 4 * h5;
      float v = fmaxf(acc[r] + bv, 0.0f);
      unsigned short h = f2bf(v);
      hi_ls[row * LDSW + col] = h;
      lo_ls[row * LDSW + col] = f2bf(v - bf2f(h));
    }
  }
  __syncthreads();

  // ---- LayerNorm ----
  {
    float g0 = ln_g[2 * lane], g1 = ln_g[2 * lane + 1];
    float be0 = ln_b[2 * lane], be1 = ln_b[2 * lane + 1];
    for (int i = 0; i < 8; ++i) {
      int row = 8 * cf + i;
      unsigned int hp = *(const unsigned int*)&hi_ls[row * LDSW + 2 * lane];
      unsigned int lp = *(const unsigned int*)&lo_ls[row * LDSW + 2 * lane];
      float v0 = bf2f((unsigned short)(hp & 0xffffu)) + bf2f((unsigned short)(lp & 0xffffu));
      float v1 = bf2f((unsigned short)(hp >> 16))     + bf2f((unsigned short)(lp >> 16));
      float s = v0 + v1, q = v0 * v0 + v1 * v1;
      #pragma unroll
      for (int off = 1; off < 64; off <<= 1) {
        s += __shfl_xor(s, off);
        q += __shfl_xor(q, off);
      }
      float mu = s * (1.0f / 128.0f);
      float var = q * (1.0f / 128.0f) - mu * mu;
      float rs = rsqrtf(var + 1e-5f);
      float o0 = (v0 - mu) * rs * g0 + be0;
      float o1 = (v1 - mu) * rs * g1 + be1;
      unsigned short h0 = f2bf(o0), h1 = f2bf(o1);
      unsigned short q0 = f2bf(o0 - bf2f(h0)), q1 = f2bf(o1 - bf2f(h1));
      *(unsigned int*)&hi_ls[row * LDSW + 2 * lane] = (unsigned int)h0 | ((unsigned int)h1 << 16);
      *(unsigned int*)&lo_ls[row * LDSW + 2 * lane] = (unsigned int)q0 | ((unsigned int)q1 << 16);
    }
  }
  __syncthreads();

  // ---- w_lin: 4 head sub-passes, write slice-major bf16 xh ----
  for (int hd = 0; hd < 4; ++hd) {
    mm_pass(8 + 4 * hd + cf, lane, phi, plo, hi_ls, lo_ls, acc);
    const int col = 32 * cf + (lane & 31);   // in-head column 0..127
    const int q = col >> 4, cin = col & 15;
    unsigned short* base = xh + (size_t)q * SLICE_U16 + hd * 16 + cin;
    #pragma unroll
    for (int r = 0; r < 16; ++r) {
      int row = (r & 3) + 8 * (r >> 2) + 4 * h5;
      base[(size_t)(row0 + row) * 64] = f2bf(acc[r]);
    }
  }
}

// ---------------------------------------------------------------------------
// attention coefficients from slice-major bf16 xh: one wave per node
// ---------------------------------------------------------------------------
__global__ __launch_bounds__(256) void k_att(
    const unsigned short* __restrict__ xh, const float* __restrict__ att_s,
    const float* __restrict__ att_d, float* __restrict__ a_src,
    float* __restrict__ a_dst)
{
  const int lane = threadIdx.x & 63;
  const int n = blockIdx.x * 4 + (threadIdx.x >> 6);
  const int head = lane >> 4;
  const int c0 = 8 * (lane & 15);         // in-head channel base
  const int q = c0 >> 4, cin = c0 & 15;   // cin in {0,8}
  uint4 xv = *(const uint4*)&xh[(size_t)q * SLICE_U16 + (size_t)n * 64 + head * 16 + cin];
  float4 s1 = *(const float4*)&att_s[head * 128 + c0];
  float4 s2 = *(const float4*)&att_s[head * 128 + c0 + 4];
  float4 d1 = *(const float4*)&att_d[head * 128 + c0];
  float4 d2 = *(const float4*)&att_d[head * 128 + c0 + 4];
  float x0 = BF_LO(xv.x), x1 = BF_HI(xv.x), x2 = BF_LO(xv.y), x3 = BF_HI(xv.y);
  float x4 = BF_LO(xv.z), x5 = BF_HI(xv.z), x6 = BF_LO(xv.w), x7 = BF_HI(xv.w);
  float ps = x0*s1.x + x1*s1.y + x2*s1.z + x3*s1.w + x4*s2.x + x5*s2.y + x6*s2.z + x7*s2.w;
  float pd = x0*d1.x + x1*d1.y + x2*d1.z + x3*d1.w + x4*d2.x + x5*d2.y + x6*d2.z + x7*d2.w;
  #pragma unroll
  for (int off = 1; off < 16; off <<= 1) {
    ps += __shfl_xor(ps, off);
    pd += __shfl_xor(pd, off);
  }
  if ((lane & 15) == 0) {
    a_src[n * 4 + head] = ps;
    a_dst[n * 4 + head] = pd;
  }
}

// ---------------------------------------------------------------------------
// CSR build: histogram -> scan -> scatter (sorted by dst)
// ---------------------------------------------------------------------------
__global__ void k_hist(const int* __restrict__ ei, int* __restrict__ count)
{
  int i = blockIdx.x * 256 + threadIdx.x;
  if (i >= E2T) return;
  int dst = (i < EE) ? ei[EE + i] : (i - EE);
  atomicAdd(&count[dst], 1);
}

// single block; counts held in registers (occupancy irrelevant), int4 I/O
__global__ __launch_bounds__(256, 1) void k_scan(const int* __restrict__ count,
                                                 int* __restrict__ offsets,
                                                 int* __restrict__ cursor)
{
  __shared__ int wtot[4];
  const int t = threadIdx.x;
  int4 buf[32];
  #pragma unroll
  for (int k = 0; k < 32; ++k) buf[k] = ((const int4*)count)[t * 32 + k];
  int s = 0;
  #pragma unroll
  for (int k = 0; k < 32; ++k) s += buf[k].x + buf[k].y + buf[k].z + buf[k].w;
  const int lane = t & 63, w = t >> 6;
  int v = s;
  #pragma unroll
  for (int off = 1; off < 64; off <<= 1) {
    int u = __shfl_up(v, off);
    if (lane >= off) v += u;
  }
  if (lane == 63) wtot[w] = v;
  __syncthreads();
  int wpre = 0;
  for (int i = 0; i < w; ++i) wpre += wtot[i];
  int run = v + wpre - s;   // exclusive prefix of this thread's chunk
  #pragma unroll
  for (int k = 0; k < 32; ++k) {
    int4 o;
    o.x = run; run += buf[k].x;
    o.y = run; run += buf[k].y;
    o.z = run; run += buf[k].z;
    o.w = run; run += buf[k].w;
    ((int4*)offsets)[t * 32 + k] = o;
    ((int4*)cursor)[t * 32 + k] = o;
  }
  if (t == 255) offsets[NN] = run;
}

__global__ void k_scatter(const int* __restrict__ ei, int* __restrict__ cursor,
                          int* __restrict__ srcs)
{
  int i = blockIdx.x * 256 + threadIdx.x;
  if (i >= E2T) return;
  int s, d;
  if (i < EE) { s = ei[i]; d = ei[EE + i]; }
  else        { s = i - EE; d = s; }
  int pos = atomicAdd(&cursor[d], 1);
  srcs[pos] = s;
}

// ---------------------------------------------------------------------------
// Edge softmax, computed ONCE: one wave per dst node -> alpha[e][4] =
// 0.25 * ex / denom  (head-mean 1/4 folded in). No-max softmax (validated).
// ---------------------------------------------------------------------------
__global__ __launch_bounds__(256) void k_edge(
    const float* __restrict__ a_src, const float* __restrict__ a_dst,
    const int* __restrict__ offsets, const int* __restrict__ srcs,
    float* __restrict__ alpha)
{
  const int lane = threadIdx.x & 63;
  const int w = threadIdx.x >> 6;
  const int n = blockIdx.x * 4 + w;
  const float4 adn = *(const float4*)&a_dst[n * 4];
  const int beg = offsets[n];
  const int deg = offsets[n + 1] - beg;

  if (deg <= 64) {
    float4 ex = {0, 0, 0, 0};
    if (lane < deg) {
      int s = __builtin_nontemporal_load(&srcs[beg + lane]);
      float4 as = *(const float4*)&a_src[s * 4];
      ex.x = __expf(lrelu(as.x + adn.x));
      ex.y = __expf(lrelu(as.y + adn.y));
      ex.z = __expf(lrelu(as.z + adn.z));
      ex.w = __expf(lrelu(as.w + adn.w));
    }
    float d0 = ex.x, d1 = ex.y, d2 = ex.z, d3 = ex.w;
    #pragma unroll
    for (int off = 1; off < 64; off <<= 1) {
      d0 += __shfl_xor(d0, off); d1 += __shfl_xor(d1, off);
      d2 += __shfl_xor(d2, off); d3 += __shfl_xor(d3, off);
    }
    if (lane < deg) {
      float4 o;
      o.x = ex.x * (0.25f / (d0 + 1e-16f));
      o.y = ex.y * (0.25f / (d1 + 1e-16f));
      o.z = ex.z * (0.25f / (d2 + 1e-16f));
      o.w = ex.w * (0.25f / (d3 + 1e-16f));
      *(float4*)&alpha[(size_t)(beg + lane) * 4] = o;
    }
  } else {
    float d0 = 0, d1 = 0, d2 = 0, d3 = 0;
    for (int j = lane; j < deg; j += 64) {
      int s = srcs[beg + j];
      float4 as = *(const float4*)&a_src[s * 4];
      float4 ex;
      ex.x = __expf(lrelu(as.x + adn.x));
      ex.y = __expf(lrelu(as.y + adn.y));
      ex.z = __expf(lrelu(as.z + adn.z));
      ex.w = __expf(lrelu(as.w + adn.w));
      d0 += ex.x; d1 += ex.y; d2 += ex.z; d3 += ex.w;
      *(float4*)&alpha[(size_t)(beg + j) * 4] = ex;
    }
    #pragma unroll
    for (int off = 1; off < 64; off <<= 1) {
      d0 += __shfl_xor(d0, off); d1 += __shfl_xor(d1, off);
      d2 += __shfl_xor(d2, off); d3 += __shfl_xor(d3, off);
    }
    float4 sc;
    sc.x = 0.25f / (d0 + 1e-16f);
    sc.y = 0.25f / (d1 + 1e-16f);
    sc.z = 0.25f / (d2 + 1e-16f);
    sc.w = 0.25f / (d3 + 1e-16f);
    for (int j = lane; j < deg; j += 64) {
      float4 ex = *(const float4*)&alpha[(size_t)(beg + j) * 4];
      ex.x *= sc.x; ex.y *= sc.y; ex.z *= sc.z; ex.w *= sc.w;
      *(float4*)&alpha[(size_t)(beg + j) * 4] = ex;
    }
  }
}

// ---------------------------------------------------------------------------
// Weighted gather, XCD-sliced: slice q = blockIdx & 7 (one 4MB xh slice per
// XCD L2). Phase A = coalesced alpha/srcs stream -> LDS (no exp, no gathers).
// Phase B: 8-lane groups x 8 edges; uint4 = 8 bf16 channels per lane.
// ---------------------------------------------------------------------------
__global__ __launch_bounds__(256) void k_gather(
    const unsigned short* __restrict__ xh, const float* __restrict__ alpha,
    const int* __restrict__ offsets, const int* __restrict__ srcs,
    const float* __restrict__ bias, float* __restrict__ out)
{
  __shared__ float4 al_ls[4][64];
  __shared__ int src_ls[4][64];
  const int lane = threadIdx.x & 63;
  const int w = threadIdx.x >> 6;
  const int q = blockIdx.x & 7;
  const int n = (blockIdx.x >> 3) * 4 + w;
  const int beg = offsets[n];
  const int deg = offsets[n + 1] - beg;
  const int hsel = (lane & 7) >> 1;
  const unsigned short* slice = xh + (size_t)q * SLICE_U16 + (lane & 7) * 8;

  float acc[8] = {0, 0, 0, 0, 0, 0, 0, 0};

  for (int j0 = 0; j0 < deg; j0 += 64) {
    int j = j0 + lane;
    float4 a4 = {0, 0, 0, 0};
    int s = 0;
    if (j < deg) {
      a4 = *(const float4*)&alpha[(size_t)(beg + j) * 4];
      s = __builtin_nontemporal_load(&srcs[beg + j]);
    }
    al_ls[w][lane] = a4;
    src_ls[w][lane] = s;
    __builtin_amdgcn_wave_barrier();
    const int cnt8 = (min(64, deg - j0) + 7) >> 3;
    #pragma unroll 4
    for (int g = 0; g < cnt8; ++g) {
      int e = g * 8 + (lane >> 3);
      float a = ((const float*)&al_ls[w][e])[hsel];
      int sv = src_ls[w][e];
      uint4 xv = *(const uint4*)(slice + (size_t)sv * 64);
      acc[0] = fmaf(a, BF_LO(xv.x), acc[0]);
      acc[1] = fmaf(a, BF_HI(xv.x), acc[1]);
      acc[2] = fmaf(a, BF_LO(xv.y), acc[2]);
      acc[3] = fmaf(a, BF_HI(xv.y), acc[3]);
      acc[4] = fmaf(a, BF_LO(xv.z), acc[4]);
      acc[5] = fmaf(a, BF_HI(xv.z), acc[5]);
      acc[6] = fmaf(a, BF_LO(xv.w), acc[6]);
      acc[7] = fmaf(a, BF_HI(xv.w), acc[7]);
    }
    __builtin_amdgcn_wave_barrier();
  }

  #pragma unroll
  for (int m = 0; m < 8; ++m) {
    float v = acc[m];
    v += __shfl_xor(v, 2);    // merge heads (lane bits 1-2)
    v += __shfl_xor(v, 4);
    v += __shfl_xor(v, 8);    // merge edge-sub groups (lane bits 3-5)
    v += __shfl_xor(v, 16);
    v += __shfl_xor(v, 32);
    acc[m] = v;
  }
  if (lane < 2) {
    const int c0 = 16 * q + 8 * lane;
    float4 o1, o2;
    o1.x = acc[0] + bias[c0 + 0];
    o1.y = acc[1] + bias[c0 + 1];
    o1.z = acc[2] + bias[c0 + 2];
    o1.w = acc[3] + bias[c0 + 3];
    o2.x = acc[4] + bias[c0 + 4];
    o2.y = acc[5] + bias[c0 + 5];
    o2.z = acc[6] + bias[c0 + 6];
    o2.w = acc[7] + bias[c0 + 7];
    *(float4*)&out[(size_t)n * HID + c0]     = o1;
    *(float4*)&out[(size_t)n * HID + c0 + 4] = o2;
  }
}

// ---------------------------------------------------------------------------
extern "C" void kernel_launch(void* const* d_in, const int* in_sizes, int n_in,
                              void* d_out, int out_size, void* d_ws, size_t ws_size,
                              hipStream_t stream)
{
  const float* x     = (const float*)d_in[0];
  const int*   ei    = (const int*)  d_in[1];
  const float* w1    = (const float*)d_in[2];
  const float* b1    = (const float*)d_in[3];
  const float* w2    = (const float*)d_in[4];
  const float* b2    = (const float*)d_in[5];
  const float* ln_g  = (const float*)d_in[6];
  const float* ln_b  = (const float*)d_in[7];
  const float* w_lin = (const float*)d_in[8];
  const float* att_s = (const float*)d_in[9];
  const float* att_d = (const float*)d_in[10];
  const float* bias  = (const float*)d_in[11];
  float* out = (float*)d_out;

  char* ws = (char*)d_ws;
  size_t off = 0;
  auto alloc = [&](size_t bytes) -> char* {
    char* p = ws + off;
    off += (bytes + 255) & ~(size_t)255;
    return p;
  };
  unsigned short* xh  = (unsigned short*)alloc((size_t)8 * SLICE_U16 * 2);  // 32 MB
  float* alpha = (float*)alloc((size_t)E2T * 4 * 4);                        // 8.9 MB
  unsigned short* phi = (unsigned short*)alloc(98304 * 2);
  unsigned short* plo = (unsigned short*)alloc(98304 * 2);
  float* a_src  = (float*)alloc((size_t)NN * 4 * 4);
  float* a_dst  = (float*)alloc((size_t)NN * 4 * 4);
  int* count    = (int*)alloc((size_t)NN * 4);
  int* offsets  = (int*)alloc((size_t)(NN + 1) * 4);
  int* cursor   = (int*)alloc((size_t)NN * 4);
  int* srcs     = (int*)alloc((size_t)E2T * 4);
  if (off > ws_size) return;

  hipMemsetAsync(count, 0, (size_t)NN * 4, stream);

  k_pack<<<384, 256, 0, stream>>>(w1, w2, w_lin, phi, plo);
  k_hist<<<(E2T + 255) / 256, 256, 0, stream>>>(ei, count);
  k_scan<<<1, 256, 0, stream>>>(count, offsets, cursor);
  k_fused<<<NN / 32, 256, 0, stream>>>(x, b1, b2, ln_g, ln_b, phi, plo, xh);
  k_scatter<<<(E2T + 255) / 256, 256, 0, stream>>>(ei, cursor, srcs);
  k_att<<<NN / 4, 256, 0, stream>>>(xh, att_s, att_d, a_src, a_dst);
  k_edge<<<NN / 4, 256, 0, stream>>>(a_src, a_dst, offsets, srcs, alpha);
  k_gather<<<(NN / 4) * 8, 256, 0, stream>>>(xh, alpha, offsets, srcs, bias, out);
}

// Round 6
// 259.435 us; speedup vs baseline: 1.2673x; 1.0545x over previous
//
#include <hip/hip_runtime.h>
#include <cstdint>

#define NN 32768
#define EE 524288
#define E2T (EE + NN)   // 557056 edges incl self loops
#define HID 128
#define LDSW 136        // u16 stride per LDS activation row (16B-aligned, bank-spread)
#define SLICE_U16 2097152  // 32768 nodes * 64 u16 per slice

typedef __attribute__((ext_vector_type(8)))  short s16x8;
typedef __attribute__((ext_vector_type(16))) float f32x16;

union V16 { uint4 u; s16x8 s; };

__device__ __forceinline__ float lrelu(float v) { return v > 0.0f ? v : 0.2f * v; }

// round-to-nearest-even f32 -> bf16
__device__ __forceinline__ unsigned short f2bf(float f) {
  unsigned int u = __float_as_uint(f);
  return (unsigned short)((u + 0x7fffu + ((u >> 16) & 1u)) >> 16);
}
__device__ __forceinline__ float bf2f(unsigned short h) {
  return __uint_as_float(((unsigned int)h) << 16);
}
#define BF_LO(u) __uint_as_float((u) << 16)
#define BF_HI(u) __uint_as_float((u) & 0xffff0000u)

// ---------------------------------------------------------------------------
// Pre-pack weights into MFMA B-fragment order, split bf16 hi/lo planes.
// ---------------------------------------------------------------------------
__global__ void k_pack(const float* __restrict__ w1, const float* __restrict__ w2,
                       const float* __restrict__ wl,
                       unsigned short* __restrict__ phi, unsigned short* __restrict__ plo)
{
  int idx = blockIdx.x * 256 + threadIdx.x;   // grid covers exactly 98304
  int r  = idx & 7;
  int l  = (idx >> 3) & 63;
  int kb = (idx >> 9) & 7;
  int s  = idx >> 12;
  const float* m; int ld, n;
  if (s < 4)      { m = w1; ld = 128; n = 32 * s       + (l & 31); }
  else if (s < 8) { m = w2; ld = 128; n = 32 * (s - 4) + (l & 31); }
  else            { m = wl; ld = 512; n = 32 * (s - 8) + (l & 31); }
  int k = 16 * kb + 8 * (l >> 5) + r;
  float f = m[(size_t)k * ld + n];
  unsigned short hi = f2bf(f);
  unsigned short lo = f2bf(f - bf2f(hi));
  phi[idx] = hi;
  plo[idx] = lo;
}

// ---------------------------------------------------------------------------
// One 32x128 @ 128x(32 per wave) GEMM pass, split-bf16 3-term MFMA.
// ---------------------------------------------------------------------------
__device__ __forceinline__ void mm_pass(int slot, int lane,
    const unsigned short* __restrict__ phi, const unsigned short* __restrict__ plo,
    const unsigned short* hi_ls, const unsigned short* lo_ls, float accv[16])
{
  f32x16 acc1 = {0,0,0,0,0,0,0,0,0,0,0,0,0,0,0,0};
  f32x16 acc2 = {0,0,0,0,0,0,0,0,0,0,0,0,0,0,0,0};
  const int arow = lane & 31;
  const int h5 = lane >> 5;
  #pragma unroll
  for (int kb = 0; kb < 8; ++kb) {
    V16 bh, bl, ah, al;
    size_t boff = ((size_t)(slot * 8 + kb) * 64 + lane) * 8;
    bh.u = *(const uint4*)&phi[boff];
    bl.u = *(const uint4*)&plo[boff];
    int aoff = arow * LDSW + 16 * kb + 8 * h5;
    ah.u = *(const uint4*)&hi_ls[aoff];
    al.u = *(const uint4*)&lo_ls[aoff];
    acc1 = __builtin_amdgcn_mfma_f32_32x32x16_bf16(ah.s, bh.s, acc1, 0, 0, 0);
    acc2 = __builtin_amdgcn_mfma_f32_32x32x16_bf16(al.s, bh.s, acc2, 0, 0, 0);
    acc2 = __builtin_amdgcn_mfma_f32_32x32x16_bf16(ah.s, bl.s, acc2, 0, 0, 0);
  }
  #pragma unroll
  for (int r = 0; r < 16; ++r) accv[r] = acc1[r] + acc2[r];
}

// ---------------------------------------------------------------------------
// Fused MLP + w_lin: 32 rows/block, 4 waves = 4 col-fragments.
// xh layout (head-minor): u16 idx = q*SLICE_U16 + node*64 + cin*4 + head,
// where q = (in-head col)>>4, cin = (in-head col)&15.
// ---------------------------------------------------------------------------
__global__ __launch_bounds__(256) void k_fused(
    const float* __restrict__ x, const float* __restrict__ b1,
    const float* __restrict__ b2, const float* __restrict__ ln_g,
    const float* __restrict__ ln_b, const unsigned short* __restrict__ phi,
    const unsigned short* __restrict__ plo, unsigned short* __restrict__ xh)
{
  __shared__ unsigned short hi_ls[32 * LDSW];
  __shared__ unsigned short lo_ls[32 * LDSW];
  const int t = threadIdx.x;
  const int lane = t & 63;
  const int cf = t >> 6;
  const int row0 = blockIdx.x * 32;
  const int h5 = lane >> 5;
  float acc[16];

  // stage x strip -> hi/lo planes
  {
    const int r = t >> 3, seg = t & 7;
    const float* src = &x[(size_t)(row0 + r) * HID + seg * 16];
    #pragma unroll
    for (int i = 0; i < 4; ++i) {
      float4 v = *(const float4*)(src + 4 * i);
      int c = seg * 16 + 4 * i;
      ushort4 h, l;
      h.x = f2bf(v.x); l.x = f2bf(v.x - bf2f(h.x));
      h.y = f2bf(v.y); l.y = f2bf(v.y - bf2f(h.y));
      h.z = f2bf(v.z); l.z = f2bf(v.z - bf2f(h.z));
      h.w = f2bf(v.w); l.w = f2bf(v.w - bf2f(h.w));
      *(ushort4*)&hi_ls[r * LDSW + c] = h;
      *(ushort4*)&lo_ls[r * LDSW + c] = l;
    }
  }
  __syncthreads();

  // ---- layer 1 ----
  mm_pass(cf, lane, phi, plo, hi_ls, lo_ls, acc);
  __syncthreads();
  {
    const int col = 32 * cf + (lane & 31);
    const float bv = b1[col];
    #pragma unroll
    for (int r = 0; r < 16; ++r) {
      int row = (r & 3) + 8 * (r >> 2) + 4 * h5;
      float v = fmaxf(acc[r] + bv, 0.0f);
      unsigned short h = f2bf(v);
      hi_ls[row * LDSW + col] = h;
      lo_ls[row * LDSW + col] = f2bf(v - bf2f(h));
    }
  }
  __syncthreads();

  // ---- layer 2 ----
  mm_pass(4 + cf, lane, phi, plo, hi_ls, lo_ls, acc);
  __syncthreads();
  {
    const int col = 32 * cf + (lane & 31);
    const float bv = b2[col];
    #pragma unroll
    for (int r = 0; r < 16; ++r) {
      int row = (r & 3) + 8 * (r >> 2) + 4 * h5;
      float v = fmaxf(acc[r] + bv, 0.0f);
      unsigned short h = f2bf(v);
      hi_ls[row * LDSW + col] = h;
      lo_ls[row * LDSW + col] = f2bf(v - bf2f(h));
    }
  }
  __syncthreads();

  // ---- LayerNorm ----
  {
    float g0 = ln_g[2 * lane], g1 = ln_g[2 * lane + 1];
    float be0 = ln_b[2 * lane], be1 = ln_b[2 * lane + 1];
    for (int i = 0; i < 8; ++i) {
      int row = 8 * cf + i;
      unsigned int hp = *(const unsigned int*)&hi_ls[row * LDSW + 2 * lane];
      unsigned int lp = *(const unsigned int*)&lo_ls[row * LDSW + 2 * lane];
      float v0 = bf2f((unsigned short)(hp & 0xffffu)) + bf2f((unsigned short)(lp & 0xffffu));
      float v1 = bf2f((unsigned short)(hp >> 16))     + bf2f((unsigned short)(lp >> 16));
      float s = v0 + v1, q = v0 * v0 + v1 * v1;
      #pragma unroll
      for (int off = 1; off < 64; off <<= 1) {
        s += __shfl_xor(s, off);
        q += __shfl_xor(q, off);
      }
      float mu = s * (1.0f / 128.0f);
      float var = q * (1.0f / 128.0f) - mu * mu;
      float rs = rsqrtf(var + 1e-5f);
      float o0 = (v0 - mu) * rs * g0 + be0;
      float o1 = (v1 - mu) * rs * g1 + be1;
      unsigned short h0 = f2bf(o0), h1 = f2bf(o1);
      unsigned short q0 = f2bf(o0 - bf2f(h0)), q1 = f2bf(o1 - bf2f(h1));
      *(unsigned int*)&hi_ls[row * LDSW + 2 * lane] = (unsigned int)h0 | ((unsigned int)h1 << 16);
      *(unsigned int*)&lo_ls[row * LDSW + 2 * lane] = (unsigned int)q0 | ((unsigned int)q1 << 16);
    }
  }
  __syncthreads();

  // ---- w_lin: 4 head sub-passes, write head-minor slice-major bf16 xh ----
  for (int hd = 0; hd < 4; ++hd) {
    mm_pass(8 + 4 * hd + cf, lane, phi, plo, hi_ls, lo_ls, acc);
    const int col = 32 * cf + (lane & 31);   // in-head column 0..127
    const int q = col >> 4, cin = col & 15;
    unsigned short* base = xh + (size_t)q * SLICE_U16 + cin * 4 + hd;
    #pragma unroll
    for (int r = 0; r < 16; ++r) {
      int row = (r & 3) + 8 * (r >> 2) + 4 * h5;
      base[(size_t)(row0 + row) * 64] = f2bf(acc[r]);
    }
  }
}

// ---------------------------------------------------------------------------
// attention coefficients from head-minor slice-major xh: one wave per node.
// lane: q = lane>>3, p = lane&7 -> uint4 = channels {16q+2p, 16q+2p+1} x 4 heads.
// ---------------------------------------------------------------------------
__global__ __launch_bounds__(256) void k_att(
    const unsigned short* __restrict__ xh, const float* __restrict__ att_s,
    const float* __restrict__ att_d, float* __restrict__ a_src,
    float* __restrict__ a_dst)
{
  const int lane = threadIdx.x & 63;
  const int n = blockIdx.x * 4 + (threadIdx.x >> 6);
  const int q = lane >> 3, p = lane & 7;
  const int c0 = 16 * q + 2 * p;
  uint4 xv = *(const uint4*)&xh[(size_t)q * SLICE_U16 + (size_t)n * 64 + p * 8];
  // xv u16[0..3] = (c0, h0..3); u16[4..7] = (c0+1, h0..3)
  float ps[4], pd[4];
  float xa0 = BF_LO(xv.x), xa1 = BF_HI(xv.x), xa2 = BF_LO(xv.y), xa3 = BF_HI(xv.y);
  float xb0 = BF_LO(xv.z), xb1 = BF_HI(xv.z), xb2 = BF_LO(xv.w), xb3 = BF_HI(xv.w);
  #pragma unroll
  for (int h = 0; h < 4; ++h) {
    float2 sv = *(const float2*)&att_s[h * 128 + c0];
    float2 dv = *(const float2*)&att_d[h * 128 + c0];
    float x0 = (h == 0) ? xa0 : (h == 1) ? xa1 : (h == 2) ? xa2 : xa3;
    float x1 = (h == 0) ? xb0 : (h == 1) ? xb1 : (h == 2) ? xb2 : xb3;
    ps[h] = x0 * sv.x + x1 * sv.y;
    pd[h] = x0 * dv.x + x1 * dv.y;
  }
  #pragma unroll
  for (int off = 1; off < 64; off <<= 1) {
    #pragma unroll
    for (int h = 0; h < 4; ++h) {
      ps[h] += __shfl_xor(ps[h], off);
      pd[h] += __shfl_xor(pd[h], off);
    }
  }
  if (lane == 0) {
    *(float4*)&a_src[n * 4] = make_float4(ps[0], ps[1], ps[2], ps[3]);
    *(float4*)&a_dst[n * 4] = make_float4(pd[0], pd[1], pd[2], pd[3]);
  }
}

// ---------------------------------------------------------------------------
// CSR build: histogram -> scan -> scatter (sorted by dst)
// ---------------------------------------------------------------------------
__global__ void k_hist(const int* __restrict__ ei, int* __restrict__ count)
{
  int i = blockIdx.x * 256 + threadIdx.x;
  if (i >= E2T) return;
  int dst = (i < EE) ? ei[EE + i] : (i - EE);
  atomicAdd(&count[dst], 1);
}

// single block; counts held in registers (occupancy irrelevant), int4 I/O
__global__ __launch_bounds__(256, 1) void k_scan(const int* __restrict__ count,
                                                 int* __restrict__ offsets,
                                                 int* __restrict__ cursor)
{
  __shared__ int wtot[4];
  const int t = threadIdx.x;
  int4 buf[32];
  #pragma unroll
  for (int k = 0; k < 32; ++k) buf[k] = ((const int4*)count)[t * 32 + k];
  int s = 0;
  #pragma unroll
  for (int k = 0; k < 32; ++k) s += buf[k].x + buf[k].y + buf[k].z + buf[k].w;
  const int lane = t & 63, w = t >> 6;
  int v = s;
  #pragma unroll
  for (int off = 1; off < 64; off <<= 1) {
    int u = __shfl_up(v, off);
    if (lane >= off) v += u;
  }
  if (lane == 63) wtot[w] = v;
  __syncthreads();
  int wpre = 0;
  for (int i = 0; i < w; ++i) wpre += wtot[i];
  int run = v + wpre - s;   // exclusive prefix of this thread's chunk
  #pragma unroll
  for (int k = 0; k < 32; ++k) {
    int4 o;
    o.x = run; run += buf[k].x;
    o.y = run; run += buf[k].y;
    o.z = run; run += buf[k].z;
    o.w = run; run += buf[k].w;
    ((int4*)offsets)[t * 32 + k] = o;
    ((int4*)cursor)[t * 32 + k] = o;
  }
  if (t == 255) offsets[NN] = run;
}

__global__ void k_scatter(const int* __restrict__ ei, int* __restrict__ cursor,
                          int* __restrict__ srcs)
{
  int i = blockIdx.x * 256 + threadIdx.x;
  if (i >= E2T) return;
  int s, d;
  if (i < EE) { s = ei[i]; d = ei[EE + i]; }
  else        { s = i - EE; d = s; }
  int pos = atomicAdd(&cursor[d], 1);
  srcs[pos] = s;
}

// ---------------------------------------------------------------------------
// Edge softmax, computed ONCE: alpha[e] = packed bf16x4 of 0.25*ex_h/denom_h.
// One wave per dst node; deg<=64 fast path (holds for this graph).
// ---------------------------------------------------------------------------
__global__ __launch_bounds__(256) void k_edge(
    const float* __restrict__ a_src, const float* __restrict__ a_dst,
    const int* __restrict__ offsets, const int* __restrict__ srcs,
    uint2* __restrict__ alpha)
{
  const int lane = threadIdx.x & 63;
  const int w = threadIdx.x >> 6;
  const int n = blockIdx.x * 4 + w;
  const float4 adn = *(const float4*)&a_dst[n * 4];
  const int beg = offsets[n];
  const int deg = offsets[n + 1] - beg;

  if (deg <= 64) {
    float4 ex = {0, 0, 0, 0};
    if (lane < deg) {
      int s = __builtin_nontemporal_load(&srcs[beg + lane]);
      float4 as = *(const float4*)&a_src[s * 4];
      ex.x = __expf(lrelu(as.x + adn.x));
      ex.y = __expf(lrelu(as.y + adn.y));
      ex.z = __expf(lrelu(as.z + adn.z));
      ex.w = __expf(lrelu(as.w + adn.w));
    }
    float d0 = ex.x, d1 = ex.y, d2 = ex.z, d3 = ex.w;
    #pragma unroll
    for (int off = 1; off < 64; off <<= 1) {
      d0 += __shfl_xor(d0, off); d1 += __shfl_xor(d1, off);
      d2 += __shfl_xor(d2, off); d3 += __shfl_xor(d3, off);
    }
    if (lane < deg) {
      float a0 = ex.x * (0.25f / (d0 + 1e-16f));
      float a1 = ex.y * (0.25f / (d1 + 1e-16f));
      float a2 = ex.z * (0.25f / (d2 + 1e-16f));
      float a3 = ex.w * (0.25f / (d3 + 1e-16f));
      uint2 u;
      u.x = (unsigned int)f2bf(a0) | ((unsigned int)f2bf(a1) << 16);
      u.y = (unsigned int)f2bf(a2) | ((unsigned int)f2bf(a3) << 16);
      alpha[beg + lane] = u;
    }
  } else {
    // slow path (not expected for this graph): recompute exp in 2nd pass
    float d0 = 0, d1 = 0, d2 = 0, d3 = 0;
    for (int j = lane; j < deg; j += 64) {
      int s = srcs[beg + j];
      float4 as = *(const float4*)&a_src[s * 4];
      d0 += __expf(lrelu(as.x + adn.x));
      d1 += __expf(lrelu(as.y + adn.y));
      d2 += __expf(lrelu(as.z + adn.z));
      d3 += __expf(lrelu(as.w + adn.w));
    }
    #pragma unroll
    for (int off = 1; off < 64; off <<= 1) {
      d0 += __shfl_xor(d0, off); d1 += __shfl_xor(d1, off);
      d2 += __shfl_xor(d2, off); d3 += __shfl_xor(d3, off);
    }
    float s0 = 0.25f / (d0 + 1e-16f), s1 = 0.25f / (d1 + 1e-16f);
    float s2 = 0.25f / (d2 + 1e-16f), s3 = 0.25f / (d3 + 1e-16f);
    for (int j = lane; j < deg; j += 64) {
      int s = srcs[beg + j];
      float4 as = *(const float4*)&a_src[s * 4];
      float a0 = __expf(lrelu(as.x + adn.x)) * s0;
      float a1 = __expf(lrelu(as.y + adn.y)) * s1;
      float a2 = __expf(lrelu(as.z + adn.z)) * s2;
      float a3 = __expf(lrelu(as.w + adn.w)) * s3;
      uint2 u;
      u.x = (unsigned int)f2bf(a0) | ((unsigned int)f2bf(a1) << 16);
      u.y = (unsigned int)f2bf(a2) | ((unsigned int)f2bf(a3) << 16);
      alpha[beg + j] = u;
    }
  }
}

// ---------------------------------------------------------------------------
// Weighted gather, XCD-sliced, head-minor: slice q = blockIdx & 7. Each wave
// handles 4 dst nodes sequentially. Per 64-edge chunk: coalesced alpha/srcs
// -> LDS; inner: 8-lane groups x 8 edges; lane = 2 out-channels, 4 heads
// summed in-place (alpha has 1/denom & 1/4 folded). Epilogue: 6 shfl/node.
// ---------------------------------------------------------------------------
__global__ __launch_bounds__(256) void k_gather(
    const unsigned short* __restrict__ xh, const uint2* __restrict__ alpha,
    const int* __restrict__ offsets, const int* __restrict__ srcs,
    const float* __restrict__ bias, float* __restrict__ out)
{
  __shared__ uint2 al_ls[4][64];
  __shared__ int src_ls[4][64];
  const int lane = threadIdx.x & 63;
  const int w = threadIdx.x >> 6;
  const int q = blockIdx.x & 7;
  const int n0 = (((blockIdx.x >> 3) * 4) + w) * 4;
  const int p = lane & 7;
  const unsigned short* slice = xh + (size_t)q * SLICE_U16 + p * 8;
  const float2 bv = *(const float2*)&bias[16 * q + 2 * p];

  for (int ni = 0; ni < 4; ++ni) {
    const int n = n0 + ni;
    const int beg = offsets[n];
    const int end = offsets[n + 1];
    float a0 = 0.0f, a1 = 0.0f;

    for (int j0 = beg; j0 < end; j0 += 64) {
      int j = j0 + lane;
      uint2 av = {0, 0};
      int s = 0;
      if (j < end) {
        av = alpha[j];
        s = __builtin_nontemporal_load(&srcs[j]);
      }
      al_ls[w][lane] = av;
      src_ls[w][lane] = s;
      __builtin_amdgcn_wave_barrier();
      const int cnt8 = (min(64, end - j0) + 7) >> 3;
      #pragma unroll 4
      for (int g = 0; g < cnt8; ++g) {
        int e = g * 8 + (lane >> 3);
        uint2 aa = al_ls[w][e];
        int sv = src_ls[w][e];
        uint4 xv = *(const uint4*)(slice + (size_t)sv * 64);
        float ah0 = BF_LO(aa.x), ah1 = BF_HI(aa.x);
        float ah2 = BF_LO(aa.y), ah3 = BF_HI(aa.y);
        a0 = fmaf(ah0, BF_LO(xv.x), a0);
        a0 = fmaf(ah1, BF_HI(xv.x), a0);
        a0 = fmaf(ah2, BF_LO(xv.y), a0);
        a0 = fmaf(ah3, BF_HI(xv.y), a0);
        a1 = fmaf(ah0, BF_LO(xv.z), a1);
        a1 = fmaf(ah1, BF_HI(xv.z), a1);
        a1 = fmaf(ah2, BF_LO(xv.w), a1);
        a1 = fmaf(ah3, BF_HI(xv.w), a1);
      }
      __builtin_amdgcn_wave_barrier();
    }

    a0 += __shfl_xor(a0, 8);  a1 += __shfl_xor(a1, 8);
    a0 += __shfl_xor(a0, 16); a1 += __shfl_xor(a1, 16);
    a0 += __shfl_xor(a0, 32); a1 += __shfl_xor(a1, 32);
    if (lane < 8) {
      float2 o = make_float2(a0 + bv.x, a1 + bv.y);
      *(float2*)&out[(size_t)n * HID + 16 * q + 2 * lane] = o;
    }
  }
}

// ---------------------------------------------------------------------------
extern "C" void kernel_launch(void* const* d_in, const int* in_sizes, int n_in,
                              void* d_out, int out_size, void* d_ws, size_t ws_size,
                              hipStream_t stream)
{
  const float* x     = (const float*)d_in[0];
  const int*   ei    = (const int*)  d_in[1];
  const float* w1    = (const float*)d_in[2];
  const float* b1    = (const float*)d_in[3];
  const float* w2    = (const float*)d_in[4];
  const float* b2    = (const float*)d_in[5];
  const float* ln_g  = (const float*)d_in[6];
  const float* ln_b  = (const float*)d_in[7];
  const float* w_lin = (const float*)d_in[8];
  const float* att_s = (const float*)d_in[9];
  const float* att_d = (const float*)d_in[10];
  const float* bias  = (const float*)d_in[11];
  float* out = (float*)d_out;

  char* ws = (char*)d_ws;
  size_t off = 0;
  auto alloc = [&](size_t bytes) -> char* {
    char* p = ws + off;
    off += (bytes + 255) & ~(size_t)255;
    return p;
  };
  unsigned short* xh  = (unsigned short*)alloc((size_t)8 * SLICE_U16 * 2);  // 32 MB
  uint2* alpha = (uint2*)alloc((size_t)E2T * 8);                            // 4.5 MB
  unsigned short* phi = (unsigned short*)alloc(98304 * 2);
  unsigned short* plo = (unsigned short*)alloc(98304 * 2);
  float* a_src  = (float*)alloc((size_t)NN * 4 * 4);
  float* a_dst  = (float*)alloc((size_t)NN * 4 * 4);
  int* count    = (int*)alloc((size_t)NN * 4);
  int* offsets  = (int*)alloc((size_t)(NN + 1) * 4);
  int* cursor   = (int*)alloc((size_t)NN * 4);
  int* srcs     = (int*)alloc((size_t)E2T * 4);
  if (off > ws_size) return;

  hipMemsetAsync(count, 0, (size_t)NN * 4, stream);

  k_pack<<<384, 256, 0, stream>>>(w1, w2, w_lin, phi, plo);
  k_hist<<<(E2T + 255) / 256, 256, 0, stream>>>(ei, count);
  k_scan<<<1, 256, 0, stream>>>(count, offsets, cursor);
  k_fused<<<NN / 32, 256, 0, stream>>>(x, b1, b2, ln_g, ln_b, phi, plo, xh);
  k_scatter<<<(E2T + 255) / 256, 256, 0, stream>>>(ei, cursor, srcs);
  k_att<<<NN / 4, 256, 0, stream>>>(xh, att_s, att_d, a_src, a_dst);
  k_edge<<<NN / 4, 256, 0, stream>>>(a_src, a_dst, offsets, srcs, alpha);
  k_gather<<<(NN / 16) * 8, 256, 0, stream>>>(xh, alpha, offsets, srcs, bias, out);
}

// Round 7
// 213.321 us; speedup vs baseline: 1.5412x; 1.2162x over previous
//
#include <hip/hip_runtime.h>
#include <cstdint>

#define NN 32768
#define EE 524288
#define E2T (EE + NN)   // 557056 edges incl self loops
#define HID 128
#define LDSW 136        // u16 stride per LDS activation row (16B-aligned, bank-spread)
#define SLICE_U16 2097152  // 32768 nodes * 64 u16 per slice

typedef __attribute__((ext_vector_type(8)))  short s16x8;
typedef __attribute__((ext_vector_type(16))) float f32x16;

union V16 { uint4 u; s16x8 s; };

__device__ __forceinline__ float lrelu(float v) { return v > 0.0f ? v : 0.2f * v; }

// round-to-nearest-even f32 -> bf16
__device__ __forceinline__ unsigned short f2bf(float f) {
  unsigned int u = __float_as_uint(f);
  return (unsigned short)((u + 0x7fffu + ((u >> 16) & 1u)) >> 16);
}
__device__ __forceinline__ float bf2f(unsigned short h) {
  return __uint_as_float(((unsigned int)h) << 16);
}
#define BF_LO(u) __uint_as_float((u) << 16)
#define BF_HI(u) __uint_as_float((u) & 0xffff0000u)

// ---------------------------------------------------------------------------
// Pre-pack weights into MFMA B-fragment order, split bf16 hi/lo planes.
// ---------------------------------------------------------------------------
__global__ void k_pack(const float* __restrict__ w1, const float* __restrict__ w2,
                       const float* __restrict__ wl,
                       unsigned short* __restrict__ phi, unsigned short* __restrict__ plo)
{
  int idx = blockIdx.x * 256 + threadIdx.x;   // grid covers exactly 98304
  int r  = idx & 7;
  int l  = (idx >> 3) & 63;
  int kb = (idx >> 9) & 7;
  int s  = idx >> 12;
  const float* m; int ld, n;
  if (s < 4)      { m = w1; ld = 128; n = 32 * s       + (l & 31); }
  else if (s < 8) { m = w2; ld = 128; n = 32 * (s - 4) + (l & 31); }
  else            { m = wl; ld = 512; n = 32 * (s - 8) + (l & 31); }
  int k = 16 * kb + 8 * (l >> 5) + r;
  float f = m[(size_t)k * ld + n];
  unsigned short hi = f2bf(f);
  unsigned short lo = f2bf(f - bf2f(hi));
  phi[idx] = hi;
  plo[idx] = lo;
}

// ---------------------------------------------------------------------------
// One 32x128 @ 128x(32 per wave) GEMM pass, split-bf16 3-term MFMA.
// ---------------------------------------------------------------------------
__device__ __forceinline__ void mm_pass(int slot, int lane,
    const unsigned short* __restrict__ phi, const unsigned short* __restrict__ plo,
    const unsigned short* hi_ls, const unsigned short* lo_ls, float accv[16])
{
  f32x16 acc1 = {0,0,0,0,0,0,0,0,0,0,0,0,0,0,0,0};
  f32x16 acc2 = {0,0,0,0,0,0,0,0,0,0,0,0,0,0,0,0};
  const int arow = lane & 31;
  const int h5 = lane >> 5;
  #pragma unroll
  for (int kb = 0; kb < 8; ++kb) {
    V16 bh, bl, ah, al;
    size_t boff = ((size_t)(slot * 8 + kb) * 64 + lane) * 8;
    bh.u = *(const uint4*)&phi[boff];
    bl.u = *(const uint4*)&plo[boff];
    int aoff = arow * LDSW + 16 * kb + 8 * h5;
    ah.u = *(const uint4*)&hi_ls[aoff];
    al.u = *(const uint4*)&lo_ls[aoff];
    acc1 = __builtin_amdgcn_mfma_f32_32x32x16_bf16(ah.s, bh.s, acc1, 0, 0, 0);
    acc2 = __builtin_amdgcn_mfma_f32_32x32x16_bf16(al.s, bh.s, acc2, 0, 0, 0);
    acc2 = __builtin_amdgcn_mfma_f32_32x32x16_bf16(ah.s, bl.s, acc2, 0, 0, 0);
  }
  #pragma unroll
  for (int r = 0; r < 16; ++r) accv[r] = acc1[r] + acc2[r];
}

// ---------------------------------------------------------------------------
// Fused MLP + w_lin + attention coefficients. 32 rows/block, 4 waves.
// w_lin output accumulated in xh_ls (head-minor layout per row:
// u16 idx_in_row = q*64 + cin*4 + head), then written coalesced to
// xh global: u16 idx = q*SLICE_U16 + node*64 + cin*4 + head.
// a_src/a_dst computed from xh_ls (replaces k_att kernel).
// ---------------------------------------------------------------------------
__global__ __launch_bounds__(256) void k_fused(
    const float* __restrict__ x, const float* __restrict__ b1,
    const float* __restrict__ b2, const float* __restrict__ ln_g,
    const float* __restrict__ ln_b, const float* __restrict__ att_s,
    const float* __restrict__ att_d, const unsigned short* __restrict__ phi,
    const unsigned short* __restrict__ plo, unsigned short* __restrict__ xh,
    float* __restrict__ a_src, float* __restrict__ a_dst)
{
  __shared__ unsigned short hi_ls[32 * LDSW];
  __shared__ unsigned short lo_ls[32 * LDSW];
  __shared__ unsigned short xh_ls[32 * 512];   // 32 KB
  const int t = threadIdx.x;
  const int lane = t & 63;
  const int cf = t >> 6;
  const int row0 = blockIdx.x * 32;
  const int h5 = lane >> 5;
  float acc[16];

  // stage x strip -> hi/lo planes
  {
    const int r = t >> 3, seg = t & 7;
    const float* src = &x[(size_t)(row0 + r) * HID + seg * 16];
    #pragma unroll
    for (int i = 0; i < 4; ++i) {
      float4 v = *(const float4*)(src + 4 * i);
      int c = seg * 16 + 4 * i;
      ushort4 h, l;
      h.x = f2bf(v.x); l.x = f2bf(v.x - bf2f(h.x));
      h.y = f2bf(v.y); l.y = f2bf(v.y - bf2f(h.y));
      h.z = f2bf(v.z); l.z = f2bf(v.z - bf2f(h.z));
      h.w = f2bf(v.w); l.w = f2bf(v.w - bf2f(h.w));
      *(ushort4*)&hi_ls[r * LDSW + c] = h;
      *(ushort4*)&lo_ls[r * LDSW + c] = l;
    }
  }
  __syncthreads();

  // ---- layer 1 ----
  mm_pass(cf, lane, phi, plo, hi_ls, lo_ls, acc);
  __syncthreads();
  {
    const int col = 32 * cf + (lane & 31);
    const float bv = b1[col];
    #pragma unroll
    for (int r = 0; r < 16; ++r) {
      int row = (r & 3) + 8 * (r >> 2) + 4 * h5;
      float v = fmaxf(acc[r] + bv, 0.0f);
      unsigned short h = f2bf(v);
      hi_ls[row * LDSW + col] = h;
      lo_ls[row * LDSW + col] = f2bf(v - bf2f(h));
    }
  }
  __syncthreads();

  // ---- layer 2 ----
  mm_pass(4 + cf, lane, phi, plo, hi_ls, lo_ls, acc);
  __syncthreads();
  {
    const int col = 32 * cf + (lane & 31);
    const float bv = b2[col];
    #pragma unroll
    for (int r = 0; r < 16; ++r) {
      int row = (r & 3) + 8 * (r >> 2) + 4 * h5;
      float v = fmaxf(acc[r] + bv, 0.0f);
      unsigned short h = f2bf(v);
      hi_ls[row * LDSW + col] = h;
      lo_ls[row * LDSW + col] = f2bf(v - bf2f(h));
    }
  }
  __syncthreads();

  // ---- LayerNorm ----
  {
    float g0 = ln_g[2 * lane], g1 = ln_g[2 * lane + 1];
    float be0 = ln_b[2 * lane], be1 = ln_b[2 * lane + 1];
    for (int i = 0; i < 8; ++i) {
      int row = 8 * cf + i;
      unsigned int hp = *(const unsigned int*)&hi_ls[row * LDSW + 2 * lane];
      unsigned int lp = *(const unsigned int*)&lo_ls[row * LDSW + 2 * lane];
      float v0 = bf2f((unsigned short)(hp & 0xffffu)) + bf2f((unsigned short)(lp & 0xffffu));
      float v1 = bf2f((unsigned short)(hp >> 16))     + bf2f((unsigned short)(lp >> 16));
      float s = v0 + v1, q = v0 * v0 + v1 * v1;
      #pragma unroll
      for (int off = 1; off < 64; off <<= 1) {
        s += __shfl_xor(s, off);
        q += __shfl_xor(q, off);
      }
      float mu = s * (1.0f / 128.0f);
      float var = q * (1.0f / 128.0f) - mu * mu;
      float rs = rsqrtf(var + 1e-5f);
      float o0 = (v0 - mu) * rs * g0 + be0;
      float o1 = (v1 - mu) * rs * g1 + be1;
      unsigned short h0 = f2bf(o0), h1 = f2bf(o1);
      unsigned short q0 = f2bf(o0 - bf2f(h0)), q1 = f2bf(o1 - bf2f(h1));
      *(unsigned int*)&hi_ls[row * LDSW + 2 * lane] = (unsigned int)h0 | ((unsigned int)h1 << 16);
      *(unsigned int*)&lo_ls[row * LDSW + 2 * lane] = (unsigned int)q0 | ((unsigned int)q1 << 16);
    }
  }
  __syncthreads();

  // ---- w_lin: 4 head sub-passes, accumulate in xh_ls (head-minor rows) ----
  for (int hd = 0; hd < 4; ++hd) {
    mm_pass(8 + 4 * hd + cf, lane, phi, plo, hi_ls, lo_ls, acc);
    const int col = 32 * cf + (lane & 31);   // in-head column 0..127
    const int q = col >> 4, cin = col & 15;
    #pragma unroll
    for (int r = 0; r < 16; ++r) {
      int row = (r & 3) + 8 * (r >> 2) + 4 * h5;
      xh_ls[row * 512 + q * 64 + cin * 4 + hd] = f2bf(acc[r]);
    }
  }
  __syncthreads();

  // ---- coalesced xh write: 16B per thread per iter ----
  for (int c8 = t; c8 < 2048; c8 += 256) {
    int base = c8 * 8;            // u16 index into xh_ls
    int row = base >> 9;
    int rem = base & 511;
    int q = rem >> 6, off = rem & 63;
    uint4 v = *(const uint4*)&xh_ls[base];
    *(uint4*)&xh[(size_t)q * SLICE_U16 + (size_t)(row0 + row) * 64 + off] = v;
  }

  // ---- attention coefficients (folded k_att): wave cf -> rows 8cf..8cf+7 ----
  {
    const int qq = lane >> 3, pp = lane & 7;
    const int c0 = 16 * qq + 2 * pp;
    float2 sh0 = *(const float2*)&att_s[0 * HID + c0];
    float2 sh1 = *(const float2*)&att_s[1 * HID + c0];
    float2 sh2 = *(const float2*)&att_s[2 * HID + c0];
    float2 sh3 = *(const float2*)&att_s[3 * HID + c0];
    float2 dh0 = *(const float2*)&att_d[0 * HID + c0];
    float2 dh1 = *(const float2*)&att_d[1 * HID + c0];
    float2 dh2 = *(const float2*)&att_d[2 * HID + c0];
    float2 dh3 = *(const float2*)&att_d[3 * HID + c0];
    for (int i = 0; i < 8; ++i) {
      int row = 8 * cf + i;
      uint4 xv = *(const uint4*)&xh_ls[row * 512 + lane * 8];
      float ps0 = BF_LO(xv.x) * sh0.x + BF_LO(xv.z) * sh0.y;
      float ps1 = BF_HI(xv.x) * sh1.x + BF_HI(xv.z) * sh1.y;
      float ps2 = BF_LO(xv.y) * sh2.x + BF_LO(xv.w) * sh2.y;
      float ps3 = BF_HI(xv.y) * sh3.x + BF_HI(xv.w) * sh3.y;
      float pd0 = BF_LO(xv.x) * dh0.x + BF_LO(xv.z) * dh0.y;
      float pd1 = BF_HI(xv.x) * dh1.x + BF_HI(xv.z) * dh1.y;
      float pd2 = BF_LO(xv.y) * dh2.x + BF_LO(xv.w) * dh2.y;
      float pd3 = BF_HI(xv.y) * dh3.x + BF_HI(xv.w) * dh3.y;
      #pragma unroll
      for (int off = 1; off < 64; off <<= 1) {
        ps0 += __shfl_xor(ps0, off); ps1 += __shfl_xor(ps1, off);
        ps2 += __shfl_xor(ps2, off); ps3 += __shfl_xor(ps3, off);
        pd0 += __shfl_xor(pd0, off); pd1 += __shfl_xor(pd1, off);
        pd2 += __shfl_xor(pd2, off); pd3 += __shfl_xor(pd3, off);
      }
      if (lane == 0) {
        *(float4*)&a_src[(size_t)(row0 + row) * 4] = make_float4(ps0, ps1, ps2, ps3);
        *(float4*)&a_dst[(size_t)(row0 + row) * 4] = make_float4(pd0, pd1, pd2, pd3);
      }
    }
  }
}

// ---------------------------------------------------------------------------
// CSR build: histogram -> scan -> scatter (sorted by dst)
// ---------------------------------------------------------------------------
__global__ void k_hist(const int* __restrict__ ei, int* __restrict__ count)
{
  int i = blockIdx.x * 256 + threadIdx.x;
  if (i >= E2T) return;
  int dst = (i < EE) ? ei[EE + i] : (i - EE);
  atomicAdd(&count[dst], 1);
}

// single block; counts held in registers (occupancy irrelevant), int4 I/O
__global__ __launch_bounds__(256, 1) void k_scan(const int* __restrict__ count,
                                                 int* __restrict__ offsets,
                                                 int* __restrict__ cursor)
{
  __shared__ int wtot[4];
  const int t = threadIdx.x;
  int4 buf[32];
  #pragma unroll
  for (int k = 0; k < 32; ++k) buf[k] = ((const int4*)count)[t * 32 + k];
  int s = 0;
  #pragma unroll
  for (int k = 0; k < 32; ++k) s += buf[k].x + buf[k].y + buf[k].z + buf[k].w;
  const int lane = t & 63, w = t >> 6;
  int v = s;
  #pragma unroll
  for (int off = 1; off < 64; off <<= 1) {
    int u = __shfl_up(v, off);
    if (lane >= off) v += u;
  }
  if (lane == 63) wtot[w] = v;
  __syncthreads();
  int wpre = 0;
  for (int i = 0; i < w; ++i) wpre += wtot[i];
  int run = v + wpre - s;   // exclusive prefix of this thread's chunk
  #pragma unroll
  for (int k = 0; k < 32; ++k) {
    int4 o;
    o.x = run; run += buf[k].x;
    o.y = run; run += buf[k].y;
    o.z = run; run += buf[k].z;
    o.w = run; run += buf[k].w;
    ((int4*)offsets)[t * 32 + k] = o;
    ((int4*)cursor)[t * 32 + k] = o;
  }
  if (t == 255) offsets[NN] = run;
}

__global__ void k_scatter(const int* __restrict__ ei, int* __restrict__ cursor,
                          int* __restrict__ srcs)
{
  int i = blockIdx.x * 256 + threadIdx.x;
  if (i >= E2T) return;
  int s, d;
  if (i < EE) { s = ei[i]; d = ei[EE + i]; }
  else        { s = i - EE; d = s; }
  int pos = atomicAdd(&cursor[d], 1);
  srcs[pos] = s;
}

// ---------------------------------------------------------------------------
// Edge softmax, computed ONCE: alpha[e] = packed bf16x4 of 0.25*ex_h/denom_h.
// One wave per dst node; deg<=64 fast path (holds for this graph).
// ---------------------------------------------------------------------------
__global__ __launch_bounds__(256) void k_edge(
    const float* __restrict__ a_src, const float* __restrict__ a_dst,
    const int* __restrict__ offsets, const int* __restrict__ srcs,
    uint2* __restrict__ alpha)
{
  const int lane = threadIdx.x & 63;
  const int w = threadIdx.x >> 6;
  const int n = blockIdx.x * 4 + w;
  const float4 adn = *(const float4*)&a_dst[n * 4];
  const int beg = offsets[n];
  const int deg = offsets[n + 1] - beg;

  if (deg <= 64) {
    float4 ex = {0, 0, 0, 0};
    if (lane < deg) {
      int s = __builtin_nontemporal_load(&srcs[beg + lane]);
      float4 as = *(const float4*)&a_src[s * 4];
      ex.x = __expf(lrelu(as.x + adn.x));
      ex.y = __expf(lrelu(as.y + adn.y));
      ex.z = __expf(lrelu(as.z + adn.z));
      ex.w = __expf(lrelu(as.w + adn.w));
    }
    float d0 = ex.x, d1 = ex.y, d2 = ex.z, d3 = ex.w;
    #pragma unroll
    for (int off = 1; off < 64; off <<= 1) {
      d0 += __shfl_xor(d0, off); d1 += __shfl_xor(d1, off);
      d2 += __shfl_xor(d2, off); d3 += __shfl_xor(d3, off);
    }
    if (lane < deg) {
      float a0 = ex.x * (0.25f / (d0 + 1e-16f));
      float a1 = ex.y * (0.25f / (d1 + 1e-16f));
      float a2 = ex.z * (0.25f / (d2 + 1e-16f));
      float a3 = ex.w * (0.25f / (d3 + 1e-16f));
      uint2 u;
      u.x = (unsigned int)f2bf(a0) | ((unsigned int)f2bf(a1) << 16);
      u.y = (unsigned int)f2bf(a2) | ((unsigned int)f2bf(a3) << 16);
      alpha[beg + lane] = u;
    }
  } else {
    // slow path (not expected for this graph): recompute exp in 2nd pass
    float d0 = 0, d1 = 0, d2 = 0, d3 = 0;
    for (int j = lane; j < deg; j += 64) {
      int s = srcs[beg + j];
      float4 as = *(const float4*)&a_src[s * 4];
      d0 += __expf(lrelu(as.x + adn.x));
      d1 += __expf(lrelu(as.y + adn.y));
      d2 += __expf(lrelu(as.z + adn.z));
      d3 += __expf(lrelu(as.w + adn.w));
    }
    #pragma unroll
    for (int off = 1; off < 64; off <<= 1) {
      d0 += __shfl_xor(d0, off); d1 += __shfl_xor(d1, off);
      d2 += __shfl_xor(d2, off); d3 += __shfl_xor(d3, off);
    }
    float s0 = 0.25f / (d0 + 1e-16f), s1 = 0.25f / (d1 + 1e-16f);
    float s2 = 0.25f / (d2 + 1e-16f), s3 = 0.25f / (d3 + 1e-16f);
    for (int j = lane; j < deg; j += 64) {
      int s = srcs[beg + j];
      float4 as = *(const float4*)&a_src[s * 4];
      float a0 = __expf(lrelu(as.x + adn.x)) * s0;
      float a1 = __expf(lrelu(as.y + adn.y)) * s1;
      float a2 = __expf(lrelu(as.z + adn.z)) * s2;
      float a3 = __expf(lrelu(as.w + adn.w)) * s3;
      uint2 u;
      u.x = (unsigned int)f2bf(a0) | ((unsigned int)f2bf(a1) << 16);
      u.y = (unsigned int)f2bf(a2) | ((unsigned int)f2bf(a3) << 16);
      alpha[beg + j] = u;
    }
  }
}

// ---------------------------------------------------------------------------
// Weighted gather v3: group-per-node. Wave = 8 groups x 8 lanes; group owns
// one dst node; lane p owns channels {16q+2p, 16q+2p+1}; 4 heads summed via
// head-minor layout. No LDS, no barriers, no cross-group reduce.
// slice q = blockIdx & 7 (XCD-resident 4MB xh slice).
// ---------------------------------------------------------------------------
__global__ __launch_bounds__(256) void k_gather(
    const unsigned short* __restrict__ xh, const uint2* __restrict__ alpha,
    const int* __restrict__ offsets, const int* __restrict__ srcs,
    const float* __restrict__ bias, float* __restrict__ out)
{
  const int lane = threadIdx.x & 63;
  const int w = threadIdx.x >> 6;
  const int q = blockIdx.x & 7;
  const int g = lane >> 3;
  const int p = lane & 7;
  const int n = (blockIdx.x >> 3) * 32 + w * 8 + g;
  const unsigned short* slice = xh + (size_t)q * SLICE_U16 + p * 8;
  const float2 bv = *(const float2*)&bias[16 * q + 2 * p];
  const int beg = offsets[n];
  const int end = offsets[n + 1];

  float a0 = 0.0f, a1 = 0.0f;
  int j = beg;
  for (; j + 2 <= end; j += 2) {
    int sv0 = srcs[j];
    int sv1 = srcs[j + 1];
    uint2 av0 = alpha[j];
    uint2 av1 = alpha[j + 1];
    uint4 xv0 = *(const uint4*)(slice + (size_t)sv0 * 64);
    uint4 xv1 = *(const uint4*)(slice + (size_t)sv1 * 64);
    a0 = fmaf(BF_LO(av0.x), BF_LO(xv0.x), a0);
    a0 = fmaf(BF_HI(av0.x), BF_HI(xv0.x), a0);
    a0 = fmaf(BF_LO(av0.y), BF_LO(xv0.y), a0);
    a0 = fmaf(BF_HI(av0.y), BF_HI(xv0.y), a0);
    a1 = fmaf(BF_LO(av0.x), BF_LO(xv0.z), a1);
    a1 = fmaf(BF_HI(av0.x), BF_HI(xv0.z), a1);
    a1 = fmaf(BF_LO(av0.y), BF_LO(xv0.w), a1);
    a1 = fmaf(BF_HI(av0.y), BF_HI(xv0.w), a1);
    a0 = fmaf(BF_LO(av1.x), BF_LO(xv1.x), a0);
    a0 = fmaf(BF_HI(av1.x), BF_HI(xv1.x), a0);
    a0 = fmaf(BF_LO(av1.y), BF_LO(xv1.y), a0);
    a0 = fmaf(BF_HI(av1.y), BF_HI(xv1.y), a0);
    a1 = fmaf(BF_LO(av1.x), BF_LO(xv1.z), a1);
    a1 = fmaf(BF_HI(av1.x), BF_HI(xv1.z), a1);
    a1 = fmaf(BF_LO(av1.y), BF_LO(xv1.w), a1);
    a1 = fmaf(BF_HI(av1.y), BF_HI(xv1.w), a1);
  }
  if (j < end) {
    int sv0 = srcs[j];
    uint2 av0 = alpha[j];
    uint4 xv0 = *(const uint4*)(slice + (size_t)sv0 * 64);
    a0 = fmaf(BF_LO(av0.x), BF_LO(xv0.x), a0);
    a0 = fmaf(BF_HI(av0.x), BF_HI(xv0.x), a0);
    a0 = fmaf(BF_LO(av0.y), BF_LO(xv0.y), a0);
    a0 = fmaf(BF_HI(av0.y), BF_HI(xv0.y), a0);
    a1 = fmaf(BF_LO(av0.x), BF_LO(xv0.z), a1);
    a1 = fmaf(BF_HI(av0.x), BF_HI(xv0.z), a1);
    a1 = fmaf(BF_LO(av0.y), BF_LO(xv0.w), a1);
    a1 = fmaf(BF_HI(av0.y), BF_HI(xv0.w), a1);
  }

  float2 o = make_float2(a0 + bv.x, a1 + bv.y);
  *(float2*)&out[(size_t)n * HID + 16 * q + 2 * p] = o;
}

// ---------------------------------------------------------------------------
extern "C" void kernel_launch(void* const* d_in, const int* in_sizes, int n_in,
                              void* d_out, int out_size, void* d_ws, size_t ws_size,
                              hipStream_t stream)
{
  const float* x     = (const float*)d_in[0];
  const int*   ei    = (const int*)  d_in[1];
  const float* w1    = (const float*)d_in[2];
  const float* b1    = (const float*)d_in[3];
  const float* w2    = (const float*)d_in[4];
  const float* b2    = (const float*)d_in[5];
  const float* ln_g  = (const float*)d_in[6];
  const float* ln_b  = (const float*)d_in[7];
  const float* w_lin = (const float*)d_in[8];
  const float* att_s = (const float*)d_in[9];
  const float* att_d = (const float*)d_in[10];
  const float* bias  = (const float*)d_in[11];
  float* out = (float*)d_out;

  char* ws = (char*)d_ws;
  size_t off = 0;
  auto alloc = [&](size_t bytes) -> char* {
    char* p = ws + off;
    off += (bytes + 255) & ~(size_t)255;
    return p;
  };
  unsigned short* xh  = (unsigned short*)alloc((size_t)8 * SLICE_U16 * 2);  // 32 MB
  uint2* alpha = (uint2*)alloc((size_t)E2T * 8);                            // 4.5 MB
  unsigned short* phi = (unsigned short*)alloc(98304 * 2);
  unsigned short* plo = (unsigned short*)alloc(98304 * 2);
  float* a_src  = (float*)alloc((size_t)NN * 4 * 4);
  float* a_dst  = (float*)alloc((size_t)NN * 4 * 4);
  int* count    = (int*)alloc((size_t)NN * 4);
  int* offsets  = (int*)alloc((size_t)(NN + 1) * 4);
  int* cursor   = (int*)alloc((size_t)NN * 4);
  int* srcs     = (int*)alloc((size_t)E2T * 4);
  if (off > ws_size) return;

  hipMemsetAsync(count, 0, (size_t)NN * 4, stream);

  k_pack<<<384, 256, 0, stream>>>(w1, w2, w_lin, phi, plo);
  k_hist<<<(E2T + 255) / 256, 256, 0, stream>>>(ei, count);
  k_scan<<<1, 256, 0, stream>>>(count, offsets, cursor);
  k_fused<<<NN / 32, 256, 0, stream>>>(x, b1, b2, ln_g, ln_b, att_s, att_d,
                                       phi, plo, xh, a_src, a_dst);
  k_scatter<<<(E2T + 255) / 256, 256, 0, stream>>>(ei, cursor, srcs);
  k_edge<<<NN / 4, 256, 0, stream>>>(a_src, a_dst, offsets, srcs, alpha);
  k_gather<<<(NN / 32) * 8, 256, 0, stream>>>(xh, alpha, offsets, srcs, bias, out);
}